// Round 1
// baseline (238.407 us; speedup 1.0000x reference)
//
#include <hip/hip_runtime.h>
#include <math.h>

// ---------------------------------------------------------------------------
// CrossViewAttention — R5: row-local mega-fusion.
// prep (unchanged) -> KV GEMMs -> mega chunk kernel (everything else, LDS
// resident, no global intermediates) -> out_kernel (unchanged).
// B=1, C=256, M=4096, W=128, H=32, BLOCKS=2, HEADS=8, DH=32
// ---------------------------------------------------------------------------

#define C_DIM 256
#define M_DIM 4096
#define W_DIM 128
#define H_DIM 32
#define ATT_SCALE 0.17677669529663687f  // 1/sqrt(32)

typedef __attribute__((ext_vector_type(8))) short short8;
typedef __attribute__((ext_vector_type(4))) short short4v;
typedef __attribute__((ext_vector_type(4))) float floatx4;

__device__ __forceinline__ unsigned short f2bf(float f) {
    unsigned u = __float_as_uint(f);
    unsigned r = (u + 0x7fffu + ((u >> 16) & 1u)) >> 16;
    return (unsigned short)r;
}
__device__ __forceinline__ float gelu_exact(float x) {
    return 0.5f * x * (1.0f + erff(x * 0.70710678118654752f));
}

// ======================= mega prep kernel (unchanged) ======================
struct PrepArgs {
    const float* grd2sat; float* xcur;
    const float* grd_x;   float* yhat;
    const float* u; int* perm; int4* chunks; int* nchunks;
    const float* win[12]; unsigned short* wout[12]; const float* wlnw[12];
    int wR[12], wC[12], wbase[13];
    const float* fW[10]; const float* flnb[10]; const float* fbase[10];
    float* fout[10];
    int fN[10], fwcol[10], focol[10];
};

__global__ __launch_bounds__(256) void prep_kernel(PrepArgs a) {
    __shared__ float smemf[9024];
    int b = blockIdx.x, t = threadIdx.x;
    if (b < 256) {
        float (*tile)[65] = (float(*)[65])smemf;
        int m0 = (b & 63) << 6, c0 = (b >> 6) << 6;
        for (int it = 0; it < 16; ++it) {
            int idx = it * 256 + t;
            int co = idx >> 6, mo = idx & 63;
            tile[co][mo] = a.grd2sat[(size_t)(c0 + co) * M_DIM + m0 + mo];
        }
        __syncthreads();
        for (int it = 0; it < 16; ++it) {
            int idx = it * 256 + t;
            int mo = idx >> 6, co = idx & 63;
            a.xcur[(size_t)(m0 + mo) * C_DIM + c0 + co] = tile[co][mo];
        }
    } else if (b < 384) {
        int idx = b - 256;
        int h = idx & 31, w0 = (idx >> 5) << 5;
        float (*tile)[33] = (float(*)[33])smemf;
        float (*ps)[32] = (float(*)[32])(smemf + 8448);
        float (*pss)[32] = (float(*)[32])(smemf + 8704);
        float* mu_s = smemf + 8960;
        float* rs_s = smemf + 8992;
        int wo = t & 31, cb = t >> 5;
        for (int it = 0; it < 32; ++it) {
            int c = it * 8 + cb;
            tile[c][wo] = a.grd_x[(size_t)c * (H_DIM * W_DIM) + h * W_DIM + w0 + wo];
        }
        __syncthreads();
        {
            int w = t & 31, part = t >> 5;
            float s = 0.f, ss = 0.f;
            for (int c = part * 32; c < part * 32 + 32; ++c) {
                float x = tile[c][w];
                s += x; ss += x * x;
            }
            ps[part][w] = s; pss[part][w] = ss;
        }
        __syncthreads();
        if (t < 32) {
            float s = 0.f, ss = 0.f;
            for (int p = 0; p < 8; ++p) { s += ps[p][t]; ss += pss[p][t]; }
            float mu = s * (1.f / 256.f);
            float var = ss * (1.f / 256.f) - mu * mu;
            mu_s[t] = mu;
            rs_s[t] = rsqrtf(var + 1e-5f);
        }
        __syncthreads();
        for (int jj = 0; jj < 32; ++jj) {
            float mu = mu_s[jj], rs = rs_s[jj];
            a.yhat[((size_t)(w0 + jj) * H_DIM + h) * C_DIM + t] =
                (tile[t][jj] - mu) * rs;
        }
    } else if (b < 1408) {
        int wI = b - 384;
        int e = 0;
        while (wI >= a.wbase[e + 1]) ++e;
        int tl = wI - a.wbase[e];
        int tilesC = a.wC[e] >> 5;
        int tr = tl / tilesC, tc = tl - tr * tilesC;
        int r0 = tr << 5, c0 = tc << 5;
        const float* in = a.win[e];
        unsigned short* out = a.wout[e];
        const float* lnw = a.wlnw[e];
        int R = a.wR[e], Cc = a.wC[e];
        float (*tile)[33] = (float(*)[33])smemf;
        int rl = t >> 3, cq = (t & 7) << 2;
        float4 v = *(const float4*)&in[(size_t)(r0 + rl) * Cc + c0 + cq];
        if (lnw) {
            float s = lnw[r0 + rl];
            v.x *= s; v.y *= s; v.z *= s; v.w *= s;
        }
        tile[rl][cq + 0] = v.x;
        tile[rl][cq + 1] = v.y;
        tile[rl][cq + 2] = v.z;
        tile[rl][cq + 3] = v.w;
        __syncthreads();
        int cl = t >> 3, rq = (t & 7) << 2;
        ushort4 o;
        o.x = f2bf(tile[rq + 0][cl]);
        o.y = f2bf(tile[rq + 1][cl]);
        o.z = f2bf(tile[rq + 2][cl]);
        o.w = f2bf(tile[rq + 3][cl]);
        *(ushort4*)&out[(size_t)(c0 + cl) * R + r0 + rq] = o;
    } else if (b < 1418) {
        int jj = b - 1408;
        int N = a.fN[jj];
        int wcol = a.fwcol[jj] + t;
        const float* W = a.fW[jj];
        const float* lb = a.flnb[jj];
        float s = a.fbase[jj] ? a.fbase[jj][wcol] : 0.f;
        for (int k = 0; k < 256; ++k) s += lb[k] * W[(size_t)k * N + wcol];
        a.fout[jj][a.focol[jj] + t] = s;
    } else {
        int* hist = (int*)smemf;
        int* cur = (int*)smemf + 128;
        unsigned short* wlb = (unsigned short*)((int*)smemf + 256);
        if (t < 128) hist[t] = 0;
        __syncthreads();
        for (int it = 0; it < 16; ++it) {
            int m = it * 256 + t;
            int wl = (int)floorf(a.u[m]);
            wl = max(0, min(wl, 126));
            wlb[m] = (unsigned short)wl;
            atomicAdd(&hist[wl], 1);
        }
        __syncthreads();
        if (t == 0) {
            int run = 0, nc = 0;
            for (int bkt = 0; bkt < 127; ++bkt) {
                int c = hist[bkt];
                cur[bkt] = run;
                int q0 = run;
                while (c > 0) {
                    int take = min(c, 32);
                    a.chunks[nc] = make_int4(bkt, q0, take, 0);
                    ++nc; q0 += take; c -= take;
                }
                run += hist[bkt];
            }
            *a.nchunks = nc;
        }
        __syncthreads();
        for (int it = 0; it < 16; ++it) {
            int m = it * 256 + t;
            int wl = wlb[m];
            int pos = atomicAdd(&cur[wl], 1);
            a.perm[pos] = m;
        }
    }
}

// ======================= templated MFMA GEMM (KV only now) =================
struct GJ {
    const void* A; const unsigned short* Bt;
    const float* bias; const float* aw; const float* ab;
    const float* rw; const float* rb; const float* res;
    float* wrz; void* out; unsigned short* out2;
    int K, N;
};

template <int LN, int EPI, int OUTM, bool WRZ, bool ABF16>
__device__ __forceinline__ void gemm_core(const GJ& j, short (*As)[264],
                                          short (*Bs)[264], int bm, int by) {
    int t = threadIdx.x;
    int bn = by << 6;
    int wv = t >> 6, lane = t & 63;
    int mt = wv & 1, nt0 = (wv >> 1) << 1;
    int quad = lane >> 4, l16 = lane & 15;
    floatx4 acc0 = {0.f, 0.f, 0.f, 0.f};
    floatx4 acc1 = {0.f, 0.f, 0.f, 0.f};
    const int K = j.K;
    for (int kc = 0; kc < K; kc += 256) {
        if (kc) __syncthreads();
        if (ABF16) {
            int ar = t >> 3, cq = (t & 7) << 5;
            const unsigned short* ap =
                (const unsigned short*)j.A + (size_t)(bm + ar) * K + kc + cq;
#pragma unroll
            for (int c = 0; c < 4; ++c)
                *(uint4*)&As[ar][cq + (c << 3)] = *(const uint4*)(ap + (c << 3));
        } else {
            int ar = t >> 3, cq = (t & 7) << 2;
            const float* ap = (const float*)j.A + (size_t)(bm + ar) * K + kc + cq;
            float4 v[8];
#pragma unroll
            for (int g = 0; g < 8; ++g) v[g] = *(const float4*)(ap + g * 32);
            if (LN >= 1) {
                float s = 0.f, ss = 0.f;
#pragma unroll
                for (int g = 0; g < 8; ++g) {
                    s += v[g].x + v[g].y + v[g].z + v[g].w;
                    ss += v[g].x * v[g].x + v[g].y * v[g].y + v[g].z * v[g].z +
                          v[g].w * v[g].w;
                }
#pragma unroll
                for (int o = 1; o < 8; o <<= 1) {
                    s += __shfl_xor(s, o, 64);
                    ss += __shfl_xor(ss, o, 64);
                }
                float mu = s * (1.f / 256.f);
                float rs = rsqrtf(ss * (1.f / 256.f) - mu * mu + 1e-5f);
#pragma unroll
                for (int g = 0; g < 8; ++g) {
                    v[g].x = (v[g].x - mu) * rs;
                    v[g].y = (v[g].y - mu) * rs;
                    v[g].z = (v[g].z - mu) * rs;
                    v[g].w = (v[g].w - mu) * rs;
                }
            }
#pragma unroll
            for (int g = 0; g < 8; ++g) {
                short4v o;
                o[0] = (short)f2bf(v[g].x);
                o[1] = (short)f2bf(v[g].y);
                o[2] = (short)f2bf(v[g].z);
                o[3] = (short)f2bf(v[g].w);
                *(short4v*)&As[ar][cq + g * 32] = o;
            }
        }
        {
            int br = t >> 2, cq2 = (t & 3) << 3;
            const unsigned short* bp = j.Bt + (size_t)(bn + br) * K + kc + cq2;
#pragma unroll
            for (int g = 0; g < 8; ++g)
                *(short8*)&Bs[br][cq2 + g * 32] = *(const short8*)(bp + g * 32);
        }
        __syncthreads();
#pragma unroll
        for (int k0 = 0; k0 < 8; ++k0) {
            short8 aa = *(const short8*)&As[(mt << 4) + l16][(k0 << 5) + (quad << 3)];
            short8 b0 = *(const short8*)&Bs[(nt0 << 4) + l16][(k0 << 5) + (quad << 3)];
            short8 b1 =
                *(const short8*)&Bs[((nt0 + 1) << 4) + l16][(k0 << 5) + (quad << 3)];
            acc0 = __builtin_amdgcn_mfma_f32_16x16x32_bf16(aa, b0, acc0, 0, 0, 0);
            acc1 = __builtin_amdgcn_mfma_f32_16x16x32_bf16(aa, b1, acc1, 0, 0, 0);
        }
    }
#pragma unroll
    for (int jj = 0; jj < 2; ++jj) {
        const floatx4 accv = jj ? acc1 : acc0;
        int col = bn + ((nt0 + jj) << 4) + l16;
        float bv = j.bias ? j.bias[col] : 0.f;
#pragma unroll
        for (int r = 0; r < 4; ++r) {
            int row = bm + (mt << 4) + (quad << 2) + r;
            float v = accv[r] + bv;
            if (OUTM == 0) {
                ((float*)j.out)[(size_t)row * j.N + col] = v;
            } else if (OUTM == 1) {
                ((unsigned short*)j.out)[(size_t)row * j.N + col] = f2bf(v);
            } else {
                if (col < 256)
                    ((unsigned short*)j.out)[(size_t)row * 256 + col] = f2bf(v);
                else
                    j.out2[(size_t)(col - 256) * M_DIM + row] = f2bf(v);
            }
        }
    }
}

// K/V for both transformer blocks: grid (128, 16)
__global__ __launch_bounds__(256) void kv_kernel(GJ j0, GJ j1) {
    __shared__ short As[32][264];
    __shared__ short Bs[64][264];
    int bm = blockIdx.x << 5;
    if ((int)blockIdx.y < 8)
        gemm_core<0, 0, 2, false, false>(j0, As, Bs, bm, blockIdx.y);
    else
        gemm_core<0, 0, 2, false, false>(j1, As, Bs, bm, blockIdx.y - 8);
}

// ======================= mega chunk kernel =================================
// One block = one 32-query chunk (same bucket wl), carried through BOTH
// transformer blocks entirely in LDS. Global I/O: xcur rows in, weights/
// K/V streamed from L2, xfinal rows out. No global intermediates.
struct MegaArgs {
    const float* xcur;
    const int* perm; const int4* chunks; const int* nchunks;
    float* xfinal;
    const unsigned short* Wq[2]; const unsigned short* Wp[2];
    const unsigned short* Wm1[2]; const unsigned short* Wm2[2];
    const unsigned short* Ktb[2]; const unsigned short* Vtb[2];
    const float* qb[2]; const float* m1b[2];
    const float* bpj[2]; const float* bm2v[2];
    const float* pw[2]; const float* pb[2];
    const float* aw; const float* ab;  // ln_post[0] for layer-1 LN2
};

// One 64-col GEMM pass: acc += A(32xK, LDS bf16, pitch lda) @ Bt[bn..bn+64)^T.
// Bt is [N][K] bf16 in global. Stages B through Bst[64][264] in 256-col chunks.
__device__ __forceinline__ void cg_pass(const short* As, int lda,
                                        const unsigned short* Bt, int K, int bn,
                                        short (*Bst)[264], floatx4& acc0,
                                        floatx4& acc1) {
    int t = threadIdx.x;
    int wv = t >> 6, lane = t & 63, quad = lane >> 4, l16 = lane & 15;
    int mt = wv & 1, nt0 = (wv >> 1) << 1;
    int br = t >> 2, cq2 = (t & 3) << 3;
#pragma unroll 1
    for (int kc = 0; kc < K; kc += 256) {
        const unsigned short* bp = Bt + (size_t)(bn + br) * K + kc + cq2;
#pragma unroll
        for (int g = 0; g < 8; ++g)
            *(short8*)&Bst[br][cq2 + (g << 5)] = *(const short8*)(bp + (g << 5));
        __syncthreads();
        const short* ap = As + (size_t)((mt << 4) + l16) * lda + kc + (quad << 3);
#pragma unroll
        for (int k0 = 0; k0 < 8; ++k0) {
            short8 aa = *(const short8*)(ap + (k0 << 5));
            short8 b0 =
                *(const short8*)&Bst[(nt0 << 4) + l16][(k0 << 5) + (quad << 3)];
            short8 b1 =
                *(const short8*)&Bst[((nt0 + 1) << 4) + l16][(k0 << 5) + (quad << 3)];
            acc0 = __builtin_amdgcn_mfma_f32_16x16x32_bf16(aa, b0, acc0, 0, 0, 0);
            acc1 = __builtin_amdgcn_mfma_f32_16x16x32_bf16(aa, b1, acc1, 0, 0, 0);
        }
        __syncthreads();
    }
}

// LDS layout (bytes), unions by lifetime:
//  [0,      33280)  U1: XH short[32][264] (stage1->Q)  /  HH short[32][520] (m1->m2)
//  [33280,  66560)  U2: QR short[32][264] (Q->attn)    /  Zf float[32][260] (proj->m2)
//  [66560,  83456)  ZH short[32][264] (LNz->m1)
//  [83456, 116736)  U4: AR short[32][264] (attn->proj) /  XO float[32][260] (m2->stage1)
//  [116736,150528)  Bst short[64][264] (GEMM stages)   /  SS float[32][69]+PB short[32][72] (attn)
//  [150528,150656)  gperm int[32]
__global__ __launch_bounds__(256) void mega_kernel(MegaArgs a) {
    __shared__ __align__(16) char smem[150656];
    short (*XH)[264] = (short(*)[264])(smem);
    short (*HH)[520] = (short(*)[520])(smem);
    short (*QR)[264] = (short(*)[264])(smem + 33280);
    float (*Zf)[260] = (float(*)[260])(smem + 33280);
    short (*ZH)[264] = (short(*)[264])(smem + 66560);
    short (*AR)[264] = (short(*)[264])(smem + 83456);
    float (*XO)[260] = (float(*)[260])(smem + 83456);
    short (*Bst)[264] = (short(*)[264])(smem + 116736);
    float (*SS)[69] = (float(*)[69])(smem + 116736);
    short (*PB)[72] = (short(*)[72])(smem + 116736 + 8832);
    int* gp = (int*)(smem + 150528);

    if ((int)blockIdx.x >= *a.nchunks) return;
    int4 cd = a.chunks[blockIdx.x];
    int wl = cd.x, qstart = cd.y, qcnt = cd.z;
    int t = threadIdx.x;
    if (t < 32) gp[t] = (t < qcnt) ? a.perm[qstart + t] : a.perm[qstart];
    __syncthreads();

    int wv = t >> 6, lane = t & 63, quad = lane >> 4, l16 = lane & 15;
    int mt = wv & 1, nt0 = (wv >> 1) << 1, ntP = wv >> 1;
    int r8 = t >> 3, cq = (t & 7) << 5;  // LN mapping: 8 lanes/row, 32 cols each
    int sg = t & 7;                       // softmax: 8 lanes/row, 8 cols each

#pragma unroll 1
    for (int l = 0; l < 2; ++l) {
        // ---------------- stage1: XH = LN(x)  (l=1: LN->ln_post0 affine->LN)
        {
            float4 v[8];
            if (l == 0) {
                const float* xp = a.xcur + (size_t)gp[r8] * 256 + cq;
#pragma unroll
                for (int g = 0; g < 8; ++g) v[g] = *(const float4*)(xp + (g << 2));
            } else {
#pragma unroll
                for (int g = 0; g < 8; ++g)
                    v[g] = *(const float4*)&XO[r8][cq + (g << 2)];
            }
            float s = 0.f, ss = 0.f;
#pragma unroll
            for (int g = 0; g < 8; ++g) {
                s += v[g].x + v[g].y + v[g].z + v[g].w;
                ss += v[g].x * v[g].x + v[g].y * v[g].y + v[g].z * v[g].z +
                      v[g].w * v[g].w;
            }
#pragma unroll
            for (int o = 1; o < 8; o <<= 1) {
                s += __shfl_xor(s, o, 64);
                ss += __shfl_xor(ss, o, 64);
            }
            float mu = s * (1.f / 256.f);
            float rs = rsqrtf(ss * (1.f / 256.f) - mu * mu + 1e-5f);
#pragma unroll
            for (int g = 0; g < 8; ++g) {
                v[g].x = (v[g].x - mu) * rs;
                v[g].y = (v[g].y - mu) * rs;
                v[g].z = (v[g].z - mu) * rs;
                v[g].w = (v[g].w - mu) * rs;
            }
            if (l == 1) {
                float s2 = 0.f, ss2 = 0.f;
#pragma unroll
                for (int g = 0; g < 8; ++g) {
                    float4 w4 = *(const float4*)&a.aw[cq + (g << 2)];
                    float4 b4 = *(const float4*)&a.ab[cq + (g << 2)];
                    v[g].x = v[g].x * w4.x + b4.x;
                    v[g].y = v[g].y * w4.y + b4.y;
                    v[g].z = v[g].z * w4.z + b4.z;
                    v[g].w = v[g].w * w4.w + b4.w;
                    s2 += v[g].x + v[g].y + v[g].z + v[g].w;
                    ss2 += v[g].x * v[g].x + v[g].y * v[g].y + v[g].z * v[g].z +
                           v[g].w * v[g].w;
                }
#pragma unroll
                for (int o = 1; o < 8; o <<= 1) {
                    s2 += __shfl_xor(s2, o, 64);
                    ss2 += __shfl_xor(ss2, o, 64);
                }
                float mu2 = s2 * (1.f / 256.f);
                float rs2 = rsqrtf(ss2 * (1.f / 256.f) - mu2 * mu2 + 1e-5f);
#pragma unroll
                for (int g = 0; g < 8; ++g) {
                    v[g].x = (v[g].x - mu2) * rs2;
                    v[g].y = (v[g].y - mu2) * rs2;
                    v[g].z = (v[g].z - mu2) * rs2;
                    v[g].w = (v[g].w - mu2) * rs2;
                }
            }
#pragma unroll
            for (int g = 0; g < 8; ++g) {
                short4v o;
                o[0] = (short)f2bf(v[g].x);
                o[1] = (short)f2bf(v[g].y);
                o[2] = (short)f2bf(v[g].z);
                o[3] = (short)f2bf(v[g].w);
                *(short4v*)&XH[r8][cq + (g << 2)] = o;
            }
        }
        __syncthreads();

        // ---------------- Q: QR = XH @ Wq'^T + qb  (bf16)
        {
            const float* qb = a.qb[l];
#pragma unroll 1
            for (int bn = 0; bn < 256; bn += 64) {
                floatx4 a0 = {0.f, 0.f, 0.f, 0.f};
                floatx4 a1 = {0.f, 0.f, 0.f, 0.f};
                cg_pass((const short*)XH, 264, a.Wq[l], 256, bn, Bst, a0, a1);
#pragma unroll
                for (int jj = 0; jj < 2; ++jj) {
                    const floatx4 av = jj ? a1 : a0;
                    int col = bn + ((nt0 + jj) << 4) + l16;
                    float bv = qb[col];
#pragma unroll
                    for (int r = 0; r < 4; ++r)
                        QR[(mt << 4) + (quad << 2) + r][col] =
                            (short)f2bf(av[r] + bv);
                }
            }
        }
        __syncthreads();

        // ---------------- attention (8 heads, K/V fragments from L2)
        {
            const unsigned short* kp0 =
                a.Ktb[l] + ((size_t)((wl << 5) + (nt0 << 4) + l16)) * 256;
            const unsigned short* kp1 = kp0 + (16 * 256);
            const unsigned short* vpb =
                a.Vtb[l] + (size_t)((ntP << 4) + l16) * M_DIM + (wl << 5);
            short8 qa = *(const short8*)&QR[(mt << 4) + l16][(quad << 3)];
            short8 kb0 = *(const short8*)(kp0 + (quad << 3));
            short8 kb1 = *(const short8*)(kp1 + (quad << 3));
            short8 va0 = *(const short8*)(vpb + (quad << 3));
            short8 va1 = *(const short8*)(vpb + 32 + (quad << 3));
#pragma unroll 1
            for (int h = 0; h < 8; ++h) {
                {  // scores -> SS[32 q][64 n]
                    floatx4 zz = {0.f, 0.f, 0.f, 0.f};
                    floatx4 c0 =
                        __builtin_amdgcn_mfma_f32_16x16x32_bf16(qa, kb0, zz, 0, 0, 0);
                    floatx4 c1 =
                        __builtin_amdgcn_mfma_f32_16x16x32_bf16(qa, kb1, zz, 0, 0, 0);
#pragma unroll
                    for (int r = 0; r < 4; ++r) {
                        int row = (mt << 4) + (quad << 2) + r;
                        SS[row][(nt0 << 4) + l16] = c0[r];
                        SS[row][((nt0 + 1) << 4) + l16] = c1[r];
                    }
                }
                // register prefetch of next head's Q/K/V fragments
                short8 nva0 = va0, nva1 = va1;
                if (h < 7) {
                    int hn = h + 1;
                    qa = *(const short8*)&QR[(mt << 4) + l16][(hn << 5) + (quad << 3)];
                    kb0 = *(const short8*)(kp0 + (hn << 5) + (quad << 3));
                    kb1 = *(const short8*)(kp1 + (hn << 5) + (quad << 3));
                    const unsigned short* vpn = vpb + (size_t)(hn << 5) * M_DIM;
                    nva0 = *(const short8*)(vpn + (quad << 3));
                    nva1 = *(const short8*)(vpn + 32 + (quad << 3));
                }
                __syncthreads();
                {  // softmax over 64 cols, normalized bf16 P
                    float e[8];
                    float s = 0.f;
#pragma unroll
                    for (int c = 0; c < 8; ++c) {
                        e[c] = __expf(SS[r8][(sg << 3) + c] * ATT_SCALE);
                        s += e[c];
                    }
                    s += __shfl_xor(s, 1, 64);
                    s += __shfl_xor(s, 2, 64);
                    s += __shfl_xor(s, 4, 64);
                    float ri = 1.f / s;
#pragma unroll
                    for (int c = 0; c < 8; ++c)
                        PB[r8][(sg << 3) + c] = (short)f2bf(e[c] * ri);
                }
                __syncthreads();
                {  // PV: AR[32 q][d], d-tile (h, ntP)
                    floatx4 acc = {0.f, 0.f, 0.f, 0.f};
#pragma unroll
                    for (int ks = 0; ks < 2; ++ks) {
                        short8 pa = *(const short8*)&PB[(mt << 4) + l16]
                                                      [(ks << 5) + (quad << 3)];
                        short8 vb = ks ? va1 : va0;
                        acc = __builtin_amdgcn_mfma_f32_16x16x32_bf16(pa, vb, acc,
                                                                      0, 0, 0);
                    }
#pragma unroll
                    for (int r = 0; r < 4; ++r)
                        AR[(mt << 4) + (quad << 2) + r]
                          [(h << 5) + (ntP << 4) + l16] = (short)f2bf(acc[r]);
                }
                va0 = nva0;
                va1 = nva1;
            }
        }
        __syncthreads();

        // ---------------- proj: Zf = AR @ Wp'^T + bproj  (fp32)
        {
            const float* bpj = a.bpj[l];
#pragma unroll 1
            for (int bn = 0; bn < 256; bn += 64) {
                floatx4 a0 = {0.f, 0.f, 0.f, 0.f};
                floatx4 a1 = {0.f, 0.f, 0.f, 0.f};
                cg_pass((const short*)AR, 264, a.Wp[l], 256, bn, Bst, a0, a1);
#pragma unroll
                for (int jj = 0; jj < 2; ++jj) {
                    const floatx4 av = jj ? a1 : a0;
                    int col = bn + ((nt0 + jj) << 4) + l16;
                    float bv = bpj[col];
#pragma unroll
                    for (int r = 0; r < 4; ++r)
                        Zf[(mt << 4) + (quad << 2) + r][col] = av[r] + bv;
                }
            }
        }
        __syncthreads();

        // ---------------- LNz: ZH = bf16(LN(Z)); Zf <- LN(Z)*pw + pb (residual)
        {
            const float* pw = a.pw[l];
            const float* pb = a.pb[l];
            float4 v[8];
#pragma unroll
            for (int g = 0; g < 8; ++g) v[g] = *(const float4*)&Zf[r8][cq + (g << 2)];
            float s = 0.f, ss = 0.f;
#pragma unroll
            for (int g = 0; g < 8; ++g) {
                s += v[g].x + v[g].y + v[g].z + v[g].w;
                ss += v[g].x * v[g].x + v[g].y * v[g].y + v[g].z * v[g].z +
                      v[g].w * v[g].w;
            }
#pragma unroll
            for (int o = 1; o < 8; o <<= 1) {
                s += __shfl_xor(s, o, 64);
                ss += __shfl_xor(ss, o, 64);
            }
            float mu = s * (1.f / 256.f);
            float rs = rsqrtf(ss * (1.f / 256.f) - mu * mu + 1e-5f);
#pragma unroll
            for (int g = 0; g < 8; ++g) {
                float4 z;
                z.x = (v[g].x - mu) * rs;
                z.y = (v[g].y - mu) * rs;
                z.z = (v[g].z - mu) * rs;
                z.w = (v[g].w - mu) * rs;
                short4v o;
                o[0] = (short)f2bf(z.x);
                o[1] = (short)f2bf(z.y);
                o[2] = (short)f2bf(z.z);
                o[3] = (short)f2bf(z.w);
                *(short4v*)&ZH[r8][cq + (g << 2)] = o;
                float4 w4 = *(const float4*)&pw[cq + (g << 2)];
                float4 b4 = *(const float4*)&pb[cq + (g << 2)];
                float4 za;
                za.x = z.x * w4.x + b4.x;
                za.y = z.y * w4.y + b4.y;
                za.z = z.z * w4.z + b4.z;
                za.w = z.w * w4.w + b4.w;
                *(float4*)&Zf[r8][cq + (g << 2)] = za;
            }
        }
        __syncthreads();

        // ---------------- m1: HH = gelu(ZH @ Wm1'^T + m1b)  (bf16, N=512)
        {
            const float* m1b = a.m1b[l];
#pragma unroll 1
            for (int bn = 0; bn < 512; bn += 64) {
                floatx4 a0 = {0.f, 0.f, 0.f, 0.f};
                floatx4 a1 = {0.f, 0.f, 0.f, 0.f};
                cg_pass((const short*)ZH, 264, a.Wm1[l], 256, bn, Bst, a0, a1);
#pragma unroll
                for (int jj = 0; jj < 2; ++jj) {
                    const floatx4 av = jj ? a1 : a0;
                    int col = bn + ((nt0 + jj) << 4) + l16;
                    float bv = m1b[col];
#pragma unroll
                    for (int r = 0; r < 4; ++r)
                        HH[(mt << 4) + (quad << 2) + r][col] =
                            (short)f2bf(gelu_exact(av[r] + bv));
                }
            }
        }
        __syncthreads();

        // ---------------- m2: x' = HH @ Wm2'^T + bm2 + Zf  (K=512)
        {
            const float* b2 = a.bm2v[l];
#pragma unroll 1
            for (int bn = 0; bn < 256; bn += 64) {
                floatx4 a0 = {0.f, 0.f, 0.f, 0.f};
                floatx4 a1 = {0.f, 0.f, 0.f, 0.f};
                cg_pass((const short*)HH, 520, a.Wm2[l], 512, bn, Bst, a0, a1);
#pragma unroll
                for (int jj = 0; jj < 2; ++jj) {
                    const floatx4 av = jj ? a1 : a0;
                    int col = bn + ((nt0 + jj) << 4) + l16;
                    float bv = b2[col];
#pragma unroll
                    for (int r = 0; r < 4; ++r) {
                        int row = (mt << 4) + (quad << 2) + r;
                        float v = av[r] + bv + Zf[row][col];
                        if (l == 0) {
                            XO[row][col] = v;
                        } else if (row < qcnt) {
                            a.xfinal[(size_t)gp[row] * 256 + col] = v;
                        }
                    }
                }
            }
        }
        __syncthreads();
    }
}

// ======================= final: LN_post + L2 norm + transpose ==============
__global__ __launch_bounds__(256) void out_kernel(const float* __restrict__ X,
                                                  const float* __restrict__ w,
                                                  const float* __restrict__ b,
                                                  float* __restrict__ out) {
    __shared__ float tile[64][65];
    int t = threadIdx.x;
    int mo = t >> 2, q = t & 3;
    int m0 = blockIdx.x << 6;
    const float* p = X + (size_t)(m0 + mo) * C_DIM + (q << 6);
    float4 v[16];
    float s = 0.f, ss = 0.f;
#pragma unroll
    for (int c = 0; c < 16; ++c) {
        v[c] = *(const float4*)(p + c * 4);
        s += v[c].x + v[c].y + v[c].z + v[c].w;
        ss += v[c].x * v[c].x + v[c].y * v[c].y + v[c].z * v[c].z + v[c].w * v[c].w;
    }
    s += __shfl_xor(s, 1, 64); s += __shfl_xor(s, 2, 64);
    ss += __shfl_xor(ss, 1, 64); ss += __shfl_xor(ss, 2, 64);
    float mu = s * (1.f / 256.f);
    float rs = rsqrtf(ss * (1.f / 256.f) - mu * mu + 1e-5f);
    float ss2 = 0.f;
#pragma unroll
    for (int c = 0; c < 16; ++c) {
        float4 w4 = *(const float4*)&w[(q << 6) + c * 4];
        float4 b4 = *(const float4*)&b[(q << 6) + c * 4];
        v[c].x = (v[c].x - mu) * rs * w4.x + b4.x;
        v[c].y = (v[c].y - mu) * rs * w4.y + b4.y;
        v[c].z = (v[c].z - mu) * rs * w4.z + b4.z;
        v[c].w = (v[c].w - mu) * rs * w4.w + b4.w;
        ss2 += v[c].x * v[c].x + v[c].y * v[c].y + v[c].z * v[c].z + v[c].w * v[c].w;
    }
    ss2 += __shfl_xor(ss2, 1, 64); ss2 += __shfl_xor(ss2, 2, 64);
    float sc = 1.f / fmaxf(sqrtf(ss2), 1e-12f);
    for (int cc = 0; cc < 4; ++cc) {
        if (q == cc) {
#pragma unroll
            for (int c = 0; c < 16; ++c) {
                tile[mo][c * 4 + 0] = v[c].x * sc;
                tile[mo][c * 4 + 1] = v[c].y * sc;
                tile[mo][c * 4 + 2] = v[c].z * sc;
                tile[mo][c * 4 + 3] = v[c].w * sc;
            }
        }
        __syncthreads();
        for (int it = 0; it < 16; ++it) {
            int idx = it * 256 + t;
            int co = idx >> 6, mr = idx & 63;
            out[(size_t)((cc << 6) + co) * M_DIM + m0 + mr] = tile[mr][co];
        }
        __syncthreads();
    }
}

// ---------------------------------------------------------------------------
extern "C" void kernel_launch(void* const* d_in, const int* in_sizes, int n_in,
                              void* d_out, int out_size, void* d_ws, size_t ws_size,
                              hipStream_t stream) {
    const float* grd2sat = (const float*)d_in[0];
    const float* grd_x   = (const float*)d_in[1];
    const float* u       = (const float*)d_in[2];
    const float* ln_q_w  = (const float*)d_in[3];
    const float* ln_q_b  = (const float*)d_in[4];
    const float* ln_k_w  = (const float*)d_in[5];
    const float* ln_k_b  = (const float*)d_in[6];
    const float* ln_v_w  = (const float*)d_in[7];
    const float* ln_v_b  = (const float*)d_in[8];
    const float* Wq      = (const float*)d_in[9];
    const float* Wk      = (const float*)d_in[10];
    const float* Wv      = (const float*)d_in[11];
    const float* Wproj   = (const float*)d_in[12];
    const float* bproj   = (const float*)d_in[13];
    const float* ln_pre_w = (const float*)d_in[14];
    const float* ln_pre_b = (const float*)d_in[15];
    const float* Wm1     = (const float*)d_in[16];
    const float* bm1     = (const float*)d_in[17];
    const float* Wm2     = (const float*)d_in[18];
    const float* bm2     = (const float*)d_in[19];
    const float* ln_post_w = (const float*)d_in[20];
    const float* ln_post_b = (const float*)d_in[21];

    float* ws   = (float*)d_ws;
    float* yhat = ws;                        // 4 MB
    float* xcur = ws + 1048576;              // 4 MB
    float* zq   = ws + 2097152;              // 4 MB (xfinal)
    unsigned short* Ktab0 = (unsigned short*)(ws + 6291456); // 2 MB
    unsigned short* Vt0   = (unsigned short*)(ws + 6815744); // 2 MB
    unsigned short* Ktab1 = (unsigned short*)(ws + 7340032); // 2 MB
    unsigned short* Vt1   = (unsigned short*)(ws + 7864320); // 2 MB
    unsigned short* Bt    = (unsigned short*)(ws + 8388608); // 2 MB (both blocks)
    float* biasbuf = ws + 8912896;           // 2560 floats
    int*  perm    = (int*)(ws + 8915456);    // 4096 ints
    int4* chunks  = (int4*)(ws + 8919552);   // 512 int4
    int*  nchunks = (int*)(ws + 8921600);
    const size_t BS = 524288;
    const size_t OQ = 0, OKV = 65536, OP = 196608, OM1 = 262144, OM2 = 393216;

    dim3 b256(256);

    PrepArgs pa;
    pa.grd2sat = grd2sat; pa.xcur = xcur;
    pa.grd_x = grd_x;     pa.yhat = yhat;
    pa.u = u; pa.perm = perm; pa.chunks = chunks; pa.nchunks = nchunks;
    {
        int base = 0;
        for (int i = 0; i < 2; ++i) {
            int e = 6 * i;
            unsigned short* bt = Bt + i * BS;
            pa.win[e+0] = Wq + i * 65536;    pa.wout[e+0] = bt + OQ;
            pa.wlnw[e+0] = ln_q_w + i * 256; pa.wR[e+0] = 256; pa.wC[e+0] = 256;
            pa.win[e+1] = Wk + i * 65536;    pa.wout[e+1] = bt + OKV;
            pa.wlnw[e+1] = ln_k_w + i * 256; pa.wR[e+1] = 256; pa.wC[e+1] = 256;
            pa.win[e+2] = Wv + i * 65536;    pa.wout[e+2] = bt + OKV + 65536;
            pa.wlnw[e+2] = ln_v_w + i * 256; pa.wR[e+2] = 256; pa.wC[e+2] = 256;
            pa.win[e+3] = Wproj + i * 65536; pa.wout[e+3] = bt + OP;
            pa.wlnw[e+3] = nullptr;          pa.wR[e+3] = 256; pa.wC[e+3] = 256;
            pa.win[e+4] = Wm1 + i * 131072;  pa.wout[e+4] = bt + OM1;
            pa.wlnw[e+4] = ln_pre_w + i * 256; pa.wR[e+4] = 256; pa.wC[e+4] = 512;
            pa.win[e+5] = Wm2 + i * 131072;  pa.wout[e+5] = bt + OM2;
            pa.wlnw[e+5] = nullptr;          pa.wR[e+5] = 512; pa.wC[e+5] = 256;
        }
        for (int e = 0; e < 12; ++e) {
            pa.wbase[e] = base;
            base += (pa.wR[e] >> 5) * (pa.wC[e] >> 5);
        }
        pa.wbase[12] = base;  // 1024
        for (int i = 0; i < 2; ++i) {
            int jb = 5 * i;
            float* bb = biasbuf + i * 1280;
            pa.fW[jb+0] = Wq + i * 65536; pa.flnb[jb+0] = ln_q_b + i * 256;
            pa.fbase[jb+0] = nullptr; pa.fout[jb+0] = bb;
            pa.fN[jb+0] = 256; pa.fwcol[jb+0] = 0; pa.focol[jb+0] = 0;
            pa.fW[jb+1] = Wk + i * 65536; pa.flnb[jb+1] = ln_k_b + i * 256;
            pa.fbase[jb+1] = nullptr; pa.fout[jb+1] = bb + 256;
            pa.fN[jb+1] = 256; pa.fwcol[jb+1] = 0; pa.focol[jb+1] = 0;
            pa.fW[jb+2] = Wv + i * 65536; pa.flnb[jb+2] = ln_v_b + i * 256;
            pa.fbase[jb+2] = nullptr; pa.fout[jb+2] = bb + 256;
            pa.fN[jb+2] = 256; pa.fwcol[jb+2] = 0; pa.focol[jb+2] = 256;
            pa.fW[jb+3] = Wm1 + i * 131072; pa.flnb[jb+3] = ln_pre_b + i * 256;
            pa.fbase[jb+3] = bm1 + i * 512; pa.fout[jb+3] = bb + 768;
            pa.fN[jb+3] = 512; pa.fwcol[jb+3] = 0; pa.focol[jb+3] = 0;
            pa.fW[jb+4] = Wm1 + i * 131072; pa.flnb[jb+4] = ln_pre_b + i * 256;
            pa.fbase[jb+4] = bm1 + i * 512; pa.fout[jb+4] = bb + 768;
            pa.fN[jb+4] = 512; pa.fwcol[jb+4] = 256; pa.focol[jb+4] = 256;
        }
    }
    prep_kernel<<<1419, b256, 0, stream>>>(pa);

    // ---- K/V tables for both transformer blocks
    GJ jkv0 = {};
    jkv0.A = yhat; jkv0.Bt = Bt + OKV; jkv0.bias = biasbuf + 256;
    jkv0.out = Ktab0; jkv0.out2 = Vt0; jkv0.K = 256; jkv0.N = 512;
    GJ jkv1 = {};
    jkv1.A = yhat; jkv1.Bt = Bt + BS + OKV; jkv1.bias = biasbuf + 1280 + 256;
    jkv1.out = Ktab1; jkv1.out2 = Vt1; jkv1.K = 256; jkv1.N = 512;
    kv_kernel<<<dim3(128, 16), b256, 0, stream>>>(jkv0, jkv1);

    // ---- mega chunk kernel (everything row-local, both layers)
    MegaArgs ma;
    ma.xcur = xcur; ma.perm = perm; ma.chunks = chunks; ma.nchunks = nchunks;
    ma.xfinal = zq;
    for (int i = 0; i < 2; ++i) {
        const unsigned short* bt = Bt + i * BS;
        ma.Wq[i] = bt + OQ; ma.Wp[i] = bt + OP;
        ma.Wm1[i] = bt + OM1; ma.Wm2[i] = bt + OM2;
        ma.Ktb[i] = i ? Ktab1 : Ktab0; ma.Vtb[i] = i ? Vt1 : Vt0;
        ma.qb[i] = biasbuf + i * 1280;
        ma.m1b[i] = biasbuf + i * 1280 + 768;
        ma.bpj[i] = bproj + i * 256;
        ma.bm2v[i] = bm2 + i * 256;
        ma.pw[i] = ln_pre_w + i * 256;
        ma.pb[i] = ln_pre_b + i * 256;
    }
    ma.aw = ln_post_w; ma.ab = ln_post_b;  // block 0 ln_post for layer-1 LN2
    mega_kernel<<<288, b256, 0, stream>>>(ma);

    out_kernel<<<64, b256, 0, stream>>>(zq, ln_post_w + 256, ln_post_b + 256,
                                        (float*)d_out);
}